// Round 2
// baseline (262.095 us; speedup 1.0000x reference)
//
#include <hip/hip_runtime.h>
#include <hip/hip_bf16.h>
#include <math.h>

#define B_ 8
#define S_ 4096
#define C_ 64
#define EPSV 1e-5f

using floatx4 = __attribute__((ext_vector_type(4))) float;
using bf16x8  = __attribute__((ext_vector_type(8))) short;
using intx4   = __attribute__((ext_vector_type(4))) int;

__device__ __forceinline__ short f2bf(float f) {
    unsigned u = __builtin_bit_cast(unsigned, f);
    u = u + 0x7fffu + ((u >> 16) & 1u);   // RNE
    return (short)(u >> 16);
}

__device__ __forceinline__ unsigned cvt_pk_bf16(float lo, float hi) {
    unsigned r;
    asm volatile("v_cvt_pk_bf16_f32 %0, %1, %2" : "=v"(r) : "v"(lo), "v"(hi));
    return r;
}

// B-fragment (or Wv A-fragment) from a row-major fp32 64x64 weight matrix:
// lane reads W[16*n + c][32*kk + 8*g .. +8] and converts to bf16.
__device__ __forceinline__ bf16x8 ld_w_frag(const float* __restrict__ W, int n, int kk, int g, int c) {
    const float* p = W + (16 * n + c) * C_ + 32 * kk + 8 * g;
    bf16x8 r;
#pragma unroll
    for (int j = 0; j < 8; ++j) r[j] = f2bf(p[j]);
    return r;
}

// ---------------- kernel 1a: per-chunk partial sums ----------------
__global__ __launch_bounds__(256) void stats1_kernel(const float* __restrict__ x,
                                                     float* __restrict__ partial) {
    int b = blockIdx.x >> 5, chunk = blockIdx.x & 31;
    const float4* xb = (const float4*)x + (size_t)b * 65536 + chunk * 2048;
    float s = 0.f, ss = 0.f;
#pragma unroll
    for (int i = 0; i < 8; ++i) {
        float4 v = xb[threadIdx.x + i * 256];
        s  += v.x + v.y + v.z + v.w;
        ss += v.x * v.x + v.y * v.y + v.z * v.z + v.w * v.w;
    }
    for (int off = 32; off > 0; off >>= 1) {
        s  += __shfl_down(s, off);
        ss += __shfl_down(ss, off);
    }
    __shared__ float sm[4], ssm[4];
    int wid = threadIdx.x >> 6, lane = threadIdx.x & 63;
    if (lane == 0) { sm[wid] = s; ssm[wid] = ss; }
    __syncthreads();
    if (threadIdx.x == 0) {
        float S = sm[0] + sm[1] + sm[2] + sm[3];
        float SS = ssm[0] + ssm[1] + ssm[2] + ssm[3];
        partial[blockIdx.x * 2]     = S;
        partial[blockIdx.x * 2 + 1] = SS;
    }
}

// ---------------- kernel 1b: finalize mean / rsqrt(var) ----------------
__global__ __launch_bounds__(512) void stats2_kernel(const float* __restrict__ partial,
                                                     float* __restrict__ stats) {
    int w = threadIdx.x >> 6, lane = threadIdx.x & 63;  // wave w = batch w
    float s = 0.f, ss = 0.f;
    if (lane < 32) {
        s  = partial[(w * 32 + lane) * 2];
        ss = partial[(w * 32 + lane) * 2 + 1];
    }
    for (int off = 16; off > 0; off >>= 1) {
        s  += __shfl_down(s, off);
        ss += __shfl_down(ss, off);
    }
    if (lane == 0) {
        const float invN = 1.0f / (float)(S_ * C_);
        float mu  = s * invN;
        float var = ss * invN - mu * mu;
        stats[w * 2]     = mu;
        stats[w * 2 + 1] = rsqrtf(var + EPSV);
    }
}

// ---------------- kernel 2: normalize + Q/K/V^T projections ----------------
__global__ __launch_bounds__(256) void proj_kernel(
    const float* __restrict__ x,
    const float* __restrict__ Wq, const float* __restrict__ bq,
    const float* __restrict__ Wk, const float* __restrict__ bk,
    const float* __restrict__ Wv, const float* __restrict__ bv,
    const float* __restrict__ stats,
    short* __restrict__ qo, short* __restrict__ ko, short* __restrict__ vto) {
    __shared__ char hbuf[64 * 128];  // [64 rows][64 bf16], XOR-swizzled

    int b  = blockIdx.x >> 6;
    int s0 = (blockIdx.x & 63) * 64;
    float mu = stats[b * 2], rs = stats[b * 2 + 1];
    const float* xt = x + ((size_t)b * S_ + s0) * C_;
    int t = threadIdx.x;

#pragma unroll
    for (int i = 0; i < 4; ++i) {
        int fi  = t + 256 * i;       // float4 index within 64x64 tile
        int row = fi >> 4;
        int c4  = fi & 15;
        float4 v = *(const float4*)(xt + row * C_ + c4 * 4);
        unsigned lo = (unsigned)(unsigned short)f2bf((v.x - mu) * rs) |
                      ((unsigned)(unsigned short)f2bf((v.y - mu) * rs) << 16);
        unsigned hi = (unsigned)(unsigned short)f2bf((v.z - mu) * rs) |
                      ((unsigned)(unsigned short)f2bf((v.w - mu) * rs) << 16);
        int off = row * 128 + c4 * 8;
        off ^= (row & 7) << 4;
        *(uint2*)(hbuf + off) = make_uint2(lo, hi);
    }
    __syncthreads();

    int lane = t & 63, w = t >> 6;
    int g = lane >> 4, c = lane & 15;

    auto ld_h = [&](int row, int kcol) -> bf16x8 {
        int off = row * 128 + kcol * 2;
        off ^= (row & 7) << 4;
        return *(const bf16x8*)(hbuf + off);
    };

    // ---- Q and K: D = h @ W^T.  A = h rows 16w..16w+15 ----
    bf16x8 ha[2];
    ha[0] = ld_h(16 * w + c, 8 * g);
    ha[1] = ld_h(16 * w + c, 32 + 8 * g);

    const float QSC = 0.125f * 1.44269504088896340736f;  // C^-0.5 * log2(e)

#pragma unroll
    for (int n = 0; n < 4; ++n) {
        floatx4 aq = {0.f, 0.f, 0.f, 0.f}, ak = {0.f, 0.f, 0.f, 0.f};
#pragma unroll
        for (int kk = 0; kk < 2; ++kk) {
            bf16x8 wq = ld_w_frag(Wq, n, kk, g, c);
            bf16x8 wk = ld_w_frag(Wk, n, kk, g, c);
            aq = __builtin_amdgcn_mfma_f32_16x16x32_bf16(ha[kk], wq, aq, 0, 0, 0);
            ak = __builtin_amdgcn_mfma_f32_16x16x32_bf16(ha[kk], wk, ak, 0, 0, 0);
        }
        float bqv = bq[16 * n + c], bkv = bk[16 * n + c];
#pragma unroll
        for (int r = 0; r < 4; ++r) {
            int srow = s0 + 16 * w + 4 * g + r;
            size_t base = ((size_t)b * S_ + srow) * C_ + 16 * n + c;
            qo[base] = f2bf((aq[r] + bqv) * QSC);
            ko[base] = f2bf(ak[r] + bkv);
        }
    }

    // ---- V^T = Wv @ h^T (direct transposed output). A = Wv rows 16w..16w+15 ----
    bf16x8 wv[2];
    wv[0] = ld_w_frag(Wv, w, 0, g, c);
    wv[1] = ld_w_frag(Wv, w, 1, g, c);
    float bvr[4];
#pragma unroll
    for (int r = 0; r < 4; ++r) bvr[r] = bv[16 * w + 4 * g + r];

#pragma unroll
    for (int n = 0; n < 4; ++n) {
        floatx4 av = {0.f, 0.f, 0.f, 0.f};
#pragma unroll
        for (int kk = 0; kk < 2; ++kk) {
            bf16x8 hb = ld_h(16 * n + c, 32 * kk + 8 * g);
            av = __builtin_amdgcn_mfma_f32_16x16x32_bf16(wv[kk], hb, av, 0, 0, 0);
        }
#pragma unroll
        for (int r = 0; r < 4; ++r) {
            int crow = 16 * w + 4 * g + r;
            vto[((size_t)b * C_ + crow) * S_ + s0 + 16 * n + c] = f2bf(av[r] + bvr[r]);
        }
    }
}

// ---------------- kernel 3: KV-split flash attention + Wo + residual ----------------
// Block = one 16-row q-tile; wave w handles KV chunk [w*1024, (w+1)*1024).
__global__ __launch_bounds__(256, 8) void flash_kernel(
    const short* __restrict__ qm, const short* __restrict__ km, const short* __restrict__ vt,
    const float* __restrict__ Wo, const float* __restrict__ bo,
    const float* __restrict__ x, float* __restrict__ out) {
    __shared__ float part[4][16][66];   // [wave][q][channel] O^T partials (unscaled)
    __shared__ float ml[4][2][16];      // [wave][m|l][q]
    __shared__ char obuf[2048];         // combined o, [16 q][64 c] bf16, XOR-swizzled

    int bid = blockIdx.x;
    int logical = (bid & 7) * 256 + (bid >> 3);  // XCD swizzle: batch b -> XCD b
    int b = logical >> 8;
    int q0 = (logical & 255) * 16;
    int t = threadIdx.x;
    int lane = t & 63, w = t >> 6;
    int g = lane >> 4, c = lane & 15;

    const short* qp = qm + (size_t)b * S_ * C_;
    const short* kp = km + (size_t)b * S_ * C_;
    const short* vp = vt + (size_t)b * C_ * S_;

    // Q^T B-fragments (held for whole loop): lane reads q row (q0+c)
    bf16x8 bqf[2];
    bqf[0] = *(const bf16x8*)(qp + (q0 + c) * C_ + 8 * g);
    bqf[1] = *(const bf16x8*)(qp + (q0 + c) * C_ + 32 + 8 * g);

    floatx4 oacc[4];
#pragma unroll
    for (int n = 0; n < 4; ++n) oacc[n] = (floatx4){0.f, 0.f, 0.f, 0.f};
    float m = -__builtin_inff(), lsum = 0.f;

    const int addr0 = ((2 * (g & 1)) * 16 + c) * 4;  // bpermute src lane*4
    const int addr1 = addr0 + 64;
    const bool kbhi = (g >> 1) != 0;

    const int kv_beg = w * (S_ / 4), kv_end_ = kv_beg + S_ / 4;
    for (int kv0 = kv_beg; kv0 < kv_end_; kv0 += 32) {
        // ---- S^T tile = K @ Q^T  (swapped so stats are per-lane) ----
        floatx4 st0 = {0.f, 0.f, 0.f, 0.f}, st1 = {0.f, 0.f, 0.f, 0.f};
#pragma unroll
        for (int kk = 0; kk < 2; ++kk) {
            bf16x8 ak0 = *(const bf16x8*)(kp + (kv0 + c) * C_ + 32 * kk + 8 * g);
            bf16x8 ak1 = *(const bf16x8*)(kp + (kv0 + 16 + c) * C_ + 32 * kk + 8 * g);
            st0 = __builtin_amdgcn_mfma_f32_16x16x32_bf16(ak0, bqf[kk], st0, 0, 0, 0);
            st1 = __builtin_amdgcn_mfma_f32_16x16x32_bf16(ak1, bqf[kk], st1, 0, 0, 0);
        }

        // ---- online softmax (q = q0 + c per lane; scores pre-scaled to log2 domain) ----
        float mt = st0[0];
        mt = fmaxf(mt, st0[1]); mt = fmaxf(mt, st0[2]); mt = fmaxf(mt, st0[3]);
        mt = fmaxf(mt, st1[0]); mt = fmaxf(mt, st1[1]);
        mt = fmaxf(mt, st1[2]); mt = fmaxf(mt, st1[3]);
        mt = fmaxf(mt, __shfl_xor(mt, 16));
        mt = fmaxf(mt, __shfl_xor(mt, 32));
        float mnew  = fmaxf(m, mt);
        float alpha = __builtin_amdgcn_exp2f(m - mnew);
        float p0[4], p1[4], psum = 0.f;
#pragma unroll
        for (int r = 0; r < 4; ++r) {
            p0[r] = __builtin_amdgcn_exp2f(st0[r] - mnew);
            p1[r] = __builtin_amdgcn_exp2f(st1[r] - mnew);
            psum += p0[r] + p1[r];
        }
        lsum = lsum * alpha + psum;
        m = mnew;
#pragma unroll
        for (int n = 0; n < 4; ++n) oacc[n] *= alpha;

        // ---- redistribute P^T into PV B-fragment via bpermute ----
        unsigned pk00 = cvt_pk_bf16(p0[0], p0[1]);
        unsigned pk01 = cvt_pk_bf16(p0[2], p0[3]);
        unsigned pk10 = cvt_pk_bf16(p1[0], p1[1]);
        unsigned pk11 = cvt_pk_bf16(p1[2], p1[3]);
        int w0a = __builtin_amdgcn_ds_bpermute(addr0, (int)pk00);
        int w0b = __builtin_amdgcn_ds_bpermute(addr0, (int)pk10);
        int w1a = __builtin_amdgcn_ds_bpermute(addr0, (int)pk01);
        int w1b = __builtin_amdgcn_ds_bpermute(addr0, (int)pk11);
        int w2a = __builtin_amdgcn_ds_bpermute(addr1, (int)pk00);
        int w2b = __builtin_amdgcn_ds_bpermute(addr1, (int)pk10);
        int w3a = __builtin_amdgcn_ds_bpermute(addr1, (int)pk01);
        int w3b = __builtin_amdgcn_ds_bpermute(addr1, (int)pk11);
        intx4 bpw;
        bpw[0] = kbhi ? w0b : w0a;
        bpw[1] = kbhi ? w1b : w1a;
        bpw[2] = kbhi ? w2b : w2a;
        bpw[3] = kbhi ? w3b : w3a;
        bf16x8 bp = __builtin_bit_cast(bf16x8, bpw);

        // ---- O^T += V^T @ P^T ----
#pragma unroll
        for (int mi = 0; mi < 4; ++mi) {
            bf16x8 av = *(const bf16x8*)(vp + (16 * mi + c) * S_ + kv0 + 8 * g);
            oacc[mi] = __builtin_amdgcn_mfma_f32_16x16x32_bf16(av, bp, oacc[mi], 0, 0, 0);
        }
    }

    // ---- per-wave finalize: reduce l across lane groups, publish partials ----
    lsum += __shfl_xor(lsum, 16);
    lsum += __shfl_xor(lsum, 32);
    if (lane < 16) {
        ml[w][0][lane] = m;
        ml[w][1][lane] = lsum;
    }
#pragma unroll
    for (int mi = 0; mi < 4; ++mi)
#pragma unroll
        for (int r = 0; r < 4; ++r)
            part[w][c][16 * mi + 4 * g + r] = oacc[mi][r];
    __syncthreads();

    // ---- cross-wave LSE combine -> bf16 o tile in obuf ----
#pragma unroll
    for (int i = 0; i < 4; ++i) {
        int idx = t + 256 * i;
        int q = idx >> 6, ch = idx & 63;
        float m0 = ml[0][0][q], m1 = ml[1][0][q], m2 = ml[2][0][q], m3 = ml[3][0][q];
        float M = fmaxf(fmaxf(m0, m1), fmaxf(m2, m3));
        float s0 = __builtin_amdgcn_exp2f(m0 - M);
        float s1 = __builtin_amdgcn_exp2f(m1 - M);
        float s2 = __builtin_amdgcn_exp2f(m2 - M);
        float s3 = __builtin_amdgcn_exp2f(m3 - M);
        float L = ml[0][1][q] * s0 + ml[1][1][q] * s1 + ml[2][1][q] * s2 + ml[3][1][q] * s3;
        float v = part[0][q][ch] * s0 + part[1][q][ch] * s1 +
                  part[2][q][ch] * s2 + part[3][q][ch] * s3;
        float o = v / L;
        int off = q * 128 + ch * 2;
        off ^= (q & 7) << 4;
        *(short*)(obuf + off) = f2bf(o);
    }
    __syncthreads();

    // ---- epilogue: out = o @ Wo^T + bo + x ; wave w takes output cols 16w..16w+15 ----
    bf16x8 ao[2];
    {
        int off0 = c * 128 + (8 * g) * 2;        off0 ^= (c & 7) << 4;
        int off1 = c * 128 + (32 + 8 * g) * 2;   off1 ^= (c & 7) << 4;
        ao[0] = *(const bf16x8*)(obuf + off0);
        ao[1] = *(const bf16x8*)(obuf + off1);
    }
    floatx4 a = {0.f, 0.f, 0.f, 0.f};
#pragma unroll
    for (int kk = 0; kk < 2; ++kk) {
        bf16x8 bw = ld_w_frag(Wo, w, kk, g, c);
        a = __builtin_amdgcn_mfma_f32_16x16x32_bf16(ao[kk], bw, a, 0, 0, 0);
    }
    float bov = bo[16 * w + c];
#pragma unroll
    for (int r = 0; r < 4; ++r) {
        int srow = q0 + 4 * g + r;
        size_t idx = ((size_t)b * S_ + srow) * C_ + 16 * w + c;
        out[idx] = x[idx] + bov + a[r];
    }
}

extern "C" void kernel_launch(void* const* d_in, const int* in_sizes, int n_in,
                              void* d_out, int out_size, void* d_ws, size_t ws_size,
                              hipStream_t stream) {
    const float* x  = (const float*)d_in[0];
    // d_in[1] = temb (unused by reference)
    const float* Wq = (const float*)d_in[2];
    const float* bq = (const float*)d_in[3];
    const float* Wk = (const float*)d_in[4];
    const float* bk = (const float*)d_in[5];
    const float* Wv = (const float*)d_in[6];
    const float* bv = (const float*)d_in[7];
    const float* Wo = (const float*)d_in[8];
    const float* bo = (const float*)d_in[9];
    float* out = (float*)d_out;

    char* ws = (char*)d_ws;
    float* partial = (float*)ws;                    // 512 floats
    float* stats   = (float*)(ws + 2048);           // 16 floats
    short* q  = (short*)(ws + 4096);                // [B][S][C] bf16
    short* k  = q + (size_t)B_ * S_ * C_;           // [B][S][C] bf16
    short* vt = k + (size_t)B_ * S_ * C_;           // [B][C][S] bf16

    stats1_kernel<<<256, 256, 0, stream>>>(x, partial);
    stats2_kernel<<<1, 512, 0, stream>>>(partial, stats);
    proj_kernel<<<B_ * (S_ / 64), 256, 0, stream>>>(x, Wq, bq, Wk, bk, Wv, bv, stats, q, k, vt);
    flash_kernel<<<B_ * (S_ / 16), 256, 0, stream>>>(q, k, vt, Wo, bo, x, out);
}

// Round 3
// 259.034 us; speedup vs baseline: 1.0118x; 1.0118x over previous
//
#include <hip/hip_runtime.h>
#include <hip/hip_bf16.h>
#include <math.h>

#define B_ 8
#define S_ 4096
#define C_ 64
#define EPSV 1e-5f

using floatx4 = __attribute__((ext_vector_type(4))) float;
using bf16x8  = __attribute__((ext_vector_type(8))) short;
using intx4   = __attribute__((ext_vector_type(4))) int;

__device__ __forceinline__ short f2bf(float f) {
    unsigned u = __builtin_bit_cast(unsigned, f);
    u = u + 0x7fffu + ((u >> 16) & 1u);   // RNE
    return (short)(u >> 16);
}

__device__ __forceinline__ unsigned cvt_pk_bf16(float lo, float hi) {
    unsigned r;
    asm volatile("v_cvt_pk_bf16_f32 %0, %1, %2" : "=v"(r) : "v"(lo), "v"(hi));
    return r;
}

// B-fragment (or Wv A-fragment) from a row-major fp32 64x64 weight matrix:
// lane reads W[16*n + c][32*kk + 8*g .. +8] and converts to bf16.
__device__ __forceinline__ bf16x8 ld_w_frag(const float* __restrict__ W, int n, int kk, int g, int c) {
    const float* p = W + (16 * n + c) * C_ + 32 * kk + 8 * g;
    bf16x8 r;
#pragma unroll
    for (int j = 0; j < 8; ++j) r[j] = f2bf(p[j]);
    return r;
}

// ---------------- kernel 1a: per-chunk partial sums ----------------
__global__ __launch_bounds__(256) void stats1_kernel(const float* __restrict__ x,
                                                     float* __restrict__ partial) {
    int b = blockIdx.x >> 5, chunk = blockIdx.x & 31;
    const float4* xb = (const float4*)x + (size_t)b * 65536 + chunk * 2048;
    float s = 0.f, ss = 0.f;
#pragma unroll
    for (int i = 0; i < 8; ++i) {
        float4 v = xb[threadIdx.x + i * 256];
        s  += v.x + v.y + v.z + v.w;
        ss += v.x * v.x + v.y * v.y + v.z * v.z + v.w * v.w;
    }
    for (int off = 32; off > 0; off >>= 1) {
        s  += __shfl_down(s, off);
        ss += __shfl_down(ss, off);
    }
    __shared__ float sm[4], ssm[4];
    int wid = threadIdx.x >> 6, lane = threadIdx.x & 63;
    if (lane == 0) { sm[wid] = s; ssm[wid] = ss; }
    __syncthreads();
    if (threadIdx.x == 0) {
        float S = sm[0] + sm[1] + sm[2] + sm[3];
        float SS = ssm[0] + ssm[1] + ssm[2] + ssm[3];
        partial[blockIdx.x * 2]     = S;
        partial[blockIdx.x * 2 + 1] = SS;
    }
}

// ---------------- kernel 1b: finalize mean / rsqrt(var) ----------------
__global__ __launch_bounds__(512) void stats2_kernel(const float* __restrict__ partial,
                                                     float* __restrict__ stats) {
    int w = threadIdx.x >> 6, lane = threadIdx.x & 63;  // wave w = batch w
    float s = 0.f, ss = 0.f;
    if (lane < 32) {
        s  = partial[(w * 32 + lane) * 2];
        ss = partial[(w * 32 + lane) * 2 + 1];
    }
    for (int off = 16; off > 0; off >>= 1) {
        s  += __shfl_down(s, off);
        ss += __shfl_down(ss, off);
    }
    if (lane == 0) {
        const float invN = 1.0f / (float)(S_ * C_);
        float mu  = s * invN;
        float var = ss * invN - mu * mu;
        stats[w * 2]     = mu;
        stats[w * 2 + 1] = rsqrtf(var + EPSV);
    }
}

// ---------------- kernel 2: normalize + Q/K/V^T projections ----------------
__global__ __launch_bounds__(256) void proj_kernel(
    const float* __restrict__ x,
    const float* __restrict__ Wq, const float* __restrict__ bq,
    const float* __restrict__ Wk, const float* __restrict__ bk,
    const float* __restrict__ Wv, const float* __restrict__ bv,
    const float* __restrict__ stats,
    short* __restrict__ qo, short* __restrict__ ko, short* __restrict__ vto) {
    __shared__ char hbuf[64 * 128];  // [64 rows][64 bf16], XOR-swizzled

    int b  = blockIdx.x >> 6;
    int s0 = (blockIdx.x & 63) * 64;
    float mu = stats[b * 2], rs = stats[b * 2 + 1];
    const float* xt = x + ((size_t)b * S_ + s0) * C_;
    int t = threadIdx.x;

#pragma unroll
    for (int i = 0; i < 4; ++i) {
        int fi  = t + 256 * i;       // float4 index within 64x64 tile
        int row = fi >> 4;
        int c4  = fi & 15;
        float4 v = *(const float4*)(xt + row * C_ + c4 * 4);
        unsigned lo = (unsigned)(unsigned short)f2bf((v.x - mu) * rs) |
                      ((unsigned)(unsigned short)f2bf((v.y - mu) * rs) << 16);
        unsigned hi = (unsigned)(unsigned short)f2bf((v.z - mu) * rs) |
                      ((unsigned)(unsigned short)f2bf((v.w - mu) * rs) << 16);
        int off = row * 128 + c4 * 8;
        off ^= (row & 7) << 4;
        *(uint2*)(hbuf + off) = make_uint2(lo, hi);
    }
    __syncthreads();

    int lane = t & 63, w = t >> 6;
    int g = lane >> 4, c = lane & 15;

    auto ld_h = [&](int row, int kcol) -> bf16x8 {
        int off = row * 128 + kcol * 2;
        off ^= (row & 7) << 4;
        return *(const bf16x8*)(hbuf + off);
    };

    // ---- Q and K: D = h @ W^T.  A = h rows 16w..16w+15 ----
    bf16x8 ha[2];
    ha[0] = ld_h(16 * w + c, 8 * g);
    ha[1] = ld_h(16 * w + c, 32 + 8 * g);

    const float QSC = 0.125f * 1.44269504088896340736f;  // C^-0.5 * log2(e)

#pragma unroll
    for (int n = 0; n < 4; ++n) {
        floatx4 aq = {0.f, 0.f, 0.f, 0.f}, ak = {0.f, 0.f, 0.f, 0.f};
#pragma unroll
        for (int kk = 0; kk < 2; ++kk) {
            bf16x8 wq = ld_w_frag(Wq, n, kk, g, c);
            bf16x8 wk = ld_w_frag(Wk, n, kk, g, c);
            aq = __builtin_amdgcn_mfma_f32_16x16x32_bf16(ha[kk], wq, aq, 0, 0, 0);
            ak = __builtin_amdgcn_mfma_f32_16x16x32_bf16(ha[kk], wk, ak, 0, 0, 0);
        }
        float bqv = bq[16 * n + c], bkv = bk[16 * n + c];
#pragma unroll
        for (int r = 0; r < 4; ++r) {
            int srow = s0 + 16 * w + 4 * g + r;
            size_t base = ((size_t)b * S_ + srow) * C_ + 16 * n + c;
            qo[base] = f2bf((aq[r] + bqv) * QSC);
            ko[base] = f2bf(ak[r] + bkv);
        }
    }

    // ---- V^T = Wv @ h^T (direct transposed output). A = Wv rows 16w..16w+15 ----
    bf16x8 wv[2];
    wv[0] = ld_w_frag(Wv, w, 0, g, c);
    wv[1] = ld_w_frag(Wv, w, 1, g, c);
    float bvr[4];
#pragma unroll
    for (int r = 0; r < 4; ++r) bvr[r] = bv[16 * w + 4 * g + r];

#pragma unroll
    for (int n = 0; n < 4; ++n) {
        floatx4 av = {0.f, 0.f, 0.f, 0.f};
#pragma unroll
        for (int kk = 0; kk < 2; ++kk) {
            bf16x8 hb = ld_h(16 * n + c, 32 * kk + 8 * g);
            av = __builtin_amdgcn_mfma_f32_16x16x32_bf16(wv[kk], hb, av, 0, 0, 0);
        }
#pragma unroll
        for (int r = 0; r < 4; ++r) {
            int crow = 16 * w + 4 * g + r;
            vto[((size_t)b * C_ + crow) * S_ + s0 + 16 * n + c] = f2bf(av[r] + bvr[r]);
        }
    }
}

// ---------------- kernel 3: KV-split flash attention + Wo + residual ----------------
// Block = one 16-row q-tile; wave w handles KV chunk [w*1024, (w+1)*1024).
// NOTE: no min-waves in launch_bounds — forcing 8/SIMD capped VGPR at 32 and
// spilled the inner loop to scratch (R2: 250us, all pipes idle). Let the
// allocator take ~52 regs; grid (8192 waves) still fills the machine.
__global__ __launch_bounds__(256) void flash_kernel(
    const short* __restrict__ qm, const short* __restrict__ km, const short* __restrict__ vt,
    const float* __restrict__ Wo, const float* __restrict__ bo,
    const float* __restrict__ x, float* __restrict__ out) {
    __shared__ float part[4][16][66];   // [wave][q][channel] O^T partials (unscaled)
    __shared__ float ml[4][2][16];      // [wave][m|l][q]
    __shared__ char obuf[2048];         // combined o, [16 q][64 c] bf16, XOR-swizzled

    int bid = blockIdx.x;
    int logical = (bid & 7) * 256 + (bid >> 3);  // XCD swizzle: batch b -> XCD b
    int b = logical >> 8;
    int q0 = (logical & 255) * 16;
    int t = threadIdx.x;
    int lane = t & 63, w = t >> 6;
    int g = lane >> 4, c = lane & 15;

    const short* qp = qm + (size_t)b * S_ * C_;
    const short* kp = km + (size_t)b * S_ * C_;
    const short* vp = vt + (size_t)b * C_ * S_;

    // Q^T B-fragments (held for whole loop): lane reads q row (q0+c)
    bf16x8 bqf[2];
    bqf[0] = *(const bf16x8*)(qp + (q0 + c) * C_ + 8 * g);
    bqf[1] = *(const bf16x8*)(qp + (q0 + c) * C_ + 32 + 8 * g);

    floatx4 oacc[4];
#pragma unroll
    for (int n = 0; n < 4; ++n) oacc[n] = (floatx4){0.f, 0.f, 0.f, 0.f};
    float m = -__builtin_inff(), lsum = 0.f;

    const int addr0 = ((2 * (g & 1)) * 16 + c) * 4;  // bpermute src lane*4
    const int addr1 = addr0 + 64;
    const bool kbhi = (g >> 1) != 0;

    const int kv_beg = w * (S_ / 4), kv_end_ = kv_beg + S_ / 4;
    for (int kv0 = kv_beg; kv0 < kv_end_; kv0 += 32) {
        // ---- S^T tile = K @ Q^T  (swapped so stats are per-lane) ----
        floatx4 st0 = {0.f, 0.f, 0.f, 0.f}, st1 = {0.f, 0.f, 0.f, 0.f};
#pragma unroll
        for (int kk = 0; kk < 2; ++kk) {
            bf16x8 ak0 = *(const bf16x8*)(kp + (kv0 + c) * C_ + 32 * kk + 8 * g);
            bf16x8 ak1 = *(const bf16x8*)(kp + (kv0 + 16 + c) * C_ + 32 * kk + 8 * g);
            st0 = __builtin_amdgcn_mfma_f32_16x16x32_bf16(ak0, bqf[kk], st0, 0, 0, 0);
            st1 = __builtin_amdgcn_mfma_f32_16x16x32_bf16(ak1, bqf[kk], st1, 0, 0, 0);
        }

        // ---- online softmax (q = q0 + c per lane; scores pre-scaled to log2 domain) ----
        float mt = st0[0];
        mt = fmaxf(mt, st0[1]); mt = fmaxf(mt, st0[2]); mt = fmaxf(mt, st0[3]);
        mt = fmaxf(mt, st1[0]); mt = fmaxf(mt, st1[1]);
        mt = fmaxf(mt, st1[2]); mt = fmaxf(mt, st1[3]);
        mt = fmaxf(mt, __shfl_xor(mt, 16));
        mt = fmaxf(mt, __shfl_xor(mt, 32));
        float mnew  = fmaxf(m, mt);
        float alpha = __builtin_amdgcn_exp2f(m - mnew);
        float p0[4], p1[4], psum = 0.f;
#pragma unroll
        for (int r = 0; r < 4; ++r) {
            p0[r] = __builtin_amdgcn_exp2f(st0[r] - mnew);
            p1[r] = __builtin_amdgcn_exp2f(st1[r] - mnew);
            psum += p0[r] + p1[r];
        }
        lsum = lsum * alpha + psum;
        m = mnew;
#pragma unroll
        for (int n = 0; n < 4; ++n) oacc[n] *= alpha;

        // ---- redistribute P^T into PV B-fragment via bpermute ----
        unsigned pk00 = cvt_pk_bf16(p0[0], p0[1]);
        unsigned pk01 = cvt_pk_bf16(p0[2], p0[3]);
        unsigned pk10 = cvt_pk_bf16(p1[0], p1[1]);
        unsigned pk11 = cvt_pk_bf16(p1[2], p1[3]);
        int w0a = __builtin_amdgcn_ds_bpermute(addr0, (int)pk00);
        int w0b = __builtin_amdgcn_ds_bpermute(addr0, (int)pk10);
        int w1a = __builtin_amdgcn_ds_bpermute(addr0, (int)pk01);
        int w1b = __builtin_amdgcn_ds_bpermute(addr0, (int)pk11);
        int w2a = __builtin_amdgcn_ds_bpermute(addr1, (int)pk00);
        int w2b = __builtin_amdgcn_ds_bpermute(addr1, (int)pk10);
        int w3a = __builtin_amdgcn_ds_bpermute(addr1, (int)pk01);
        int w3b = __builtin_amdgcn_ds_bpermute(addr1, (int)pk11);
        intx4 bpw;
        bpw[0] = kbhi ? w0b : w0a;
        bpw[1] = kbhi ? w1b : w1a;
        bpw[2] = kbhi ? w2b : w2a;
        bpw[3] = kbhi ? w3b : w3a;
        bf16x8 bp = __builtin_bit_cast(bf16x8, bpw);

        // ---- O^T += V^T @ P^T ----
#pragma unroll
        for (int mi = 0; mi < 4; ++mi) {
            bf16x8 av = *(const bf16x8*)(vp + (16 * mi + c) * S_ + kv0 + 8 * g);
            oacc[mi] = __builtin_amdgcn_mfma_f32_16x16x32_bf16(av, bp, oacc[mi], 0, 0, 0);
        }
    }

    // ---- per-wave finalize: reduce l across lane groups, publish partials ----
    lsum += __shfl_xor(lsum, 16);
    lsum += __shfl_xor(lsum, 32);
    if (lane < 16) {
        ml[w][0][lane] = m;
        ml[w][1][lane] = lsum;
    }
#pragma unroll
    for (int mi = 0; mi < 4; ++mi)
#pragma unroll
        for (int r = 0; r < 4; ++r)
            part[w][c][16 * mi + 4 * g + r] = oacc[mi][r];
    __syncthreads();

    // ---- cross-wave LSE combine -> bf16 o tile in obuf ----
#pragma unroll
    for (int i = 0; i < 4; ++i) {
        int idx = t + 256 * i;
        int q = idx >> 6, ch = idx & 63;
        float m0 = ml[0][0][q], m1 = ml[1][0][q], m2 = ml[2][0][q], m3 = ml[3][0][q];
        float M = fmaxf(fmaxf(m0, m1), fmaxf(m2, m3));
        float s0 = __builtin_amdgcn_exp2f(m0 - M);
        float s1 = __builtin_amdgcn_exp2f(m1 - M);
        float s2 = __builtin_amdgcn_exp2f(m2 - M);
        float s3 = __builtin_amdgcn_exp2f(m3 - M);
        float L = ml[0][1][q] * s0 + ml[1][1][q] * s1 + ml[2][1][q] * s2 + ml[3][1][q] * s3;
        float v = part[0][q][ch] * s0 + part[1][q][ch] * s1 +
                  part[2][q][ch] * s2 + part[3][q][ch] * s3;
        float o = v / L;
        int off = q * 128 + ch * 2;
        off ^= (q & 7) << 4;
        *(short*)(obuf + off) = f2bf(o);
    }
    __syncthreads();

    // ---- epilogue: out = o @ Wo^T + bo + x ; wave w takes output cols 16w..16w+15 ----
    bf16x8 ao[2];
    {
        int off0 = c * 128 + (8 * g) * 2;        off0 ^= (c & 7) << 4;
        int off1 = c * 128 + (32 + 8 * g) * 2;   off1 ^= (c & 7) << 4;
        ao[0] = *(const bf16x8*)(obuf + off0);
        ao[1] = *(const bf16x8*)(obuf + off1);
    }
    floatx4 a = {0.f, 0.f, 0.f, 0.f};
#pragma unroll
    for (int kk = 0; kk < 2; ++kk) {
        bf16x8 bw = ld_w_frag(Wo, w, kk, g, c);
        a = __builtin_amdgcn_mfma_f32_16x16x32_bf16(ao[kk], bw, a, 0, 0, 0);
    }
    float bov = bo[16 * w + c];
#pragma unroll
    for (int r = 0; r < 4; ++r) {
        int srow = q0 + 4 * g + r;
        size_t idx = ((size_t)b * S_ + srow) * C_ + 16 * w + c;
        out[idx] = x[idx] + bov + a[r];
    }
}

extern "C" void kernel_launch(void* const* d_in, const int* in_sizes, int n_in,
                              void* d_out, int out_size, void* d_ws, size_t ws_size,
                              hipStream_t stream) {
    const float* x  = (const float*)d_in[0];
    // d_in[1] = temb (unused by reference)
    const float* Wq = (const float*)d_in[2];
    const float* bq = (const float*)d_in[3];
    const float* Wk = (const float*)d_in[4];
    const float* bk = (const float*)d_in[5];
    const float* Wv = (const float*)d_in[6];
    const float* bv = (const float*)d_in[7];
    const float* Wo = (const float*)d_in[8];
    const float* bo = (const float*)d_in[9];
    float* out = (float*)d_out;

    char* ws = (char*)d_ws;
    float* partial = (float*)ws;                    // 512 floats
    float* stats   = (float*)(ws + 2048);           // 16 floats
    short* q  = (short*)(ws + 4096);                // [B][S][C] bf16
    short* k  = q + (size_t)B_ * S_ * C_;           // [B][S][C] bf16
    short* vt = k + (size_t)B_ * S_ * C_;           // [B][C][S] bf16

    stats1_kernel<<<256, 256, 0, stream>>>(x, partial);
    stats2_kernel<<<1, 512, 0, stream>>>(partial, stats);
    proj_kernel<<<B_ * (S_ / 64), 256, 0, stream>>>(x, Wq, bq, Wk, bk, Wv, bv, stats, q, k, vt);
    flash_kernel<<<B_ * (S_ / 16), 256, 0, stream>>>(q, k, vt, Wo, bo, x, out);
}

// Round 4
// 204.728 us; speedup vs baseline: 1.2802x; 1.2653x over previous
//
#include <hip/hip_runtime.h>
#include <hip/hip_bf16.h>
#include <math.h>

#define B_ 8
#define S_ 4096
#define C_ 64
#define EPSV 1e-5f

using floatx4 = __attribute__((ext_vector_type(4))) float;
using bf16x8  = __attribute__((ext_vector_type(8))) short;
using intx4   = __attribute__((ext_vector_type(4))) int;

__device__ __forceinline__ short f2bf(float f) {
    unsigned u = __builtin_bit_cast(unsigned, f);
    u = u + 0x7fffu + ((u >> 16) & 1u);   // RNE
    return (short)(u >> 16);
}

__device__ __forceinline__ unsigned cvt_pk_bf16(float lo, float hi) {
    unsigned r;
    asm volatile("v_cvt_pk_bf16_f32 %0, %1, %2" : "=v"(r) : "v"(lo), "v"(hi));
    return r;
}

// B-fragment (or Wv A-fragment) from a row-major fp32 64x64 weight matrix:
// lane reads W[16*n + c][32*kk + 8*g .. +8] and converts to bf16.
__device__ __forceinline__ bf16x8 ld_w_frag(const float* __restrict__ W, int n, int kk, int g, int c) {
    const float* p = W + (16 * n + c) * C_ + 32 * kk + 8 * g;
    bf16x8 r;
#pragma unroll
    for (int j = 0; j < 8; ++j) r[j] = f2bf(p[j]);
    return r;
}

// ---------------- kernel 1a: per-chunk partial sums ----------------
__global__ __launch_bounds__(256) void stats1_kernel(const float* __restrict__ x,
                                                     float* __restrict__ partial) {
    int b = blockIdx.x >> 5, chunk = blockIdx.x & 31;
    const float4* xb = (const float4*)x + (size_t)b * 65536 + chunk * 2048;
    float s = 0.f, ss = 0.f;
#pragma unroll
    for (int i = 0; i < 8; ++i) {
        float4 v = xb[threadIdx.x + i * 256];
        s  += v.x + v.y + v.z + v.w;
        ss += v.x * v.x + v.y * v.y + v.z * v.z + v.w * v.w;
    }
    for (int off = 32; off > 0; off >>= 1) {
        s  += __shfl_down(s, off);
        ss += __shfl_down(ss, off);
    }
    __shared__ float sm[4], ssm[4];
    int wid = threadIdx.x >> 6, lane = threadIdx.x & 63;
    if (lane == 0) { sm[wid] = s; ssm[wid] = ss; }
    __syncthreads();
    if (threadIdx.x == 0) {
        float S = sm[0] + sm[1] + sm[2] + sm[3];
        float SS = ssm[0] + ssm[1] + ssm[2] + ssm[3];
        partial[blockIdx.x * 2]     = S;
        partial[blockIdx.x * 2 + 1] = SS;
    }
}

// ---------------- kernel 1b: finalize mean / rsqrt(var) ----------------
__global__ __launch_bounds__(512) void stats2_kernel(const float* __restrict__ partial,
                                                     float* __restrict__ stats) {
    int w = threadIdx.x >> 6, lane = threadIdx.x & 63;  // wave w = batch w
    float s = 0.f, ss = 0.f;
    if (lane < 32) {
        s  = partial[(w * 32 + lane) * 2];
        ss = partial[(w * 32 + lane) * 2 + 1];
    }
    for (int off = 16; off > 0; off >>= 1) {
        s  += __shfl_down(s, off);
        ss += __shfl_down(ss, off);
    }
    if (lane == 0) {
        const float invN = 1.0f / (float)(S_ * C_);
        float mu  = s * invN;
        float var = ss * invN - mu * mu;
        stats[w * 2]     = mu;
        stats[w * 2 + 1] = rsqrtf(var + EPSV);
    }
}

// ---------------- kernel 2: normalize + Q/K/V^T projections ----------------
// V^T is written TILED: [B*4 mi][S/32 t][16 cr][32 u] bf16 so that the flash
// kernel's V loads are contiguous lane-linear 1KB blocks. (R3 post-mortem:
// 8KB-strided V rows alias all 16 lines of each load to one L2 channel ->
// fixed ~250us wall invariant to occupancy.)
__global__ __launch_bounds__(256) void proj_kernel(
    const float* __restrict__ x,
    const float* __restrict__ Wq, const float* __restrict__ bq,
    const float* __restrict__ Wk, const float* __restrict__ bk,
    const float* __restrict__ Wv, const float* __restrict__ bv,
    const float* __restrict__ stats,
    short* __restrict__ qo, short* __restrict__ ko, short* __restrict__ vto) {
    __shared__ char hbuf[64 * 128];  // [64 rows][64 bf16], XOR-swizzled

    int b  = blockIdx.x >> 6;
    int s0 = (blockIdx.x & 63) * 64;
    float mu = stats[b * 2], rs = stats[b * 2 + 1];
    const float* xt = x + ((size_t)b * S_ + s0) * C_;
    int t = threadIdx.x;

#pragma unroll
    for (int i = 0; i < 4; ++i) {
        int fi  = t + 256 * i;       // float4 index within 64x64 tile
        int row = fi >> 4;
        int c4  = fi & 15;
        float4 v = *(const float4*)(xt + row * C_ + c4 * 4);
        unsigned lo = (unsigned)(unsigned short)f2bf((v.x - mu) * rs) |
                      ((unsigned)(unsigned short)f2bf((v.y - mu) * rs) << 16);
        unsigned hi = (unsigned)(unsigned short)f2bf((v.z - mu) * rs) |
                      ((unsigned)(unsigned short)f2bf((v.w - mu) * rs) << 16);
        int off = row * 128 + c4 * 8;
        off ^= (row & 7) << 4;
        *(uint2*)(hbuf + off) = make_uint2(lo, hi);
    }
    __syncthreads();

    int lane = t & 63, w = t >> 6;
    int g = lane >> 4, c = lane & 15;

    auto ld_h = [&](int row, int kcol) -> bf16x8 {
        int off = row * 128 + kcol * 2;
        off ^= (row & 7) << 4;
        return *(const bf16x8*)(hbuf + off);
    };

    // ---- Q and K: D = h @ W^T.  A = h rows 16w..16w+15 ----
    bf16x8 ha[2];
    ha[0] = ld_h(16 * w + c, 8 * g);
    ha[1] = ld_h(16 * w + c, 32 + 8 * g);

    const float QSC = 0.125f * 1.44269504088896340736f;  // C^-0.5 * log2(e)

#pragma unroll
    for (int n = 0; n < 4; ++n) {
        floatx4 aq = {0.f, 0.f, 0.f, 0.f}, ak = {0.f, 0.f, 0.f, 0.f};
#pragma unroll
        for (int kk = 0; kk < 2; ++kk) {
            bf16x8 wq = ld_w_frag(Wq, n, kk, g, c);
            bf16x8 wk = ld_w_frag(Wk, n, kk, g, c);
            aq = __builtin_amdgcn_mfma_f32_16x16x32_bf16(ha[kk], wq, aq, 0, 0, 0);
            ak = __builtin_amdgcn_mfma_f32_16x16x32_bf16(ha[kk], wk, ak, 0, 0, 0);
        }
        float bqv = bq[16 * n + c], bkv = bk[16 * n + c];
#pragma unroll
        for (int r = 0; r < 4; ++r) {
            int srow = s0 + 16 * w + 4 * g + r;
            size_t base = ((size_t)b * S_ + srow) * C_ + 16 * n + c;
            qo[base] = f2bf((aq[r] + bqv) * QSC);
            ko[base] = f2bf(ak[r] + bkv);
        }
    }

    // ---- V^T = Wv @ h^T (direct transposed output, tiled layout). ----
    bf16x8 wv[2];
    wv[0] = ld_w_frag(Wv, w, 0, g, c);
    wv[1] = ld_w_frag(Wv, w, 1, g, c);
    float bvr[4];
#pragma unroll
    for (int r = 0; r < 4; ++r) bvr[r] = bv[16 * w + 4 * g + r];

#pragma unroll
    for (int n = 0; n < 4; ++n) {
        floatx4 av = {0.f, 0.f, 0.f, 0.f};
#pragma unroll
        for (int kk = 0; kk < 2; ++kk) {
            bf16x8 hb = ld_h(16 * n + c, 32 * kk + 8 * g);
            av = __builtin_amdgcn_mfma_f32_16x16x32_bf16(wv[kk], hb, av, 0, 0, 0);
        }
        // channel = 16*w + 4*g + r (mi = w, cr = 4g+r); s = s0 + 16n + c
        // tile index t = s0/32 + (n>>1); within-tile col u = 16*(n&1) + c
        size_t tbase = (((size_t)b * 4 + w) * 128 + (s0 >> 5) + (n >> 1)) * 512;
#pragma unroll
        for (int r = 0; r < 4; ++r) {
            vto[tbase + (4 * g + r) * 32 + 16 * (n & 1) + c] = f2bf(av[r] + bvr[r]);
        }
    }
}

// ---------------- kernel 3: KV-split flash attention + Wo + residual ----------------
// Block = one 16-row q-tile; wave w handles KV chunk [w*1024, (w+1)*1024).
__global__ __launch_bounds__(256) void flash_kernel(
    const short* __restrict__ qm, const short* __restrict__ km, const short* __restrict__ vt,
    const float* __restrict__ Wo, const float* __restrict__ bo,
    const float* __restrict__ x, float* __restrict__ out) {
    __shared__ float part[4][16][66];   // [wave][q][channel] O^T partials (unscaled)
    __shared__ float ml[4][2][16];      // [wave][m|l][q]
    __shared__ char obuf[2048];         // combined o, [16 q][64 c] bf16, XOR-swizzled

    int bid = blockIdx.x;
    int logical = (bid & 7) * 256 + (bid >> 3);  // XCD swizzle: batch b -> XCD b
    int b = logical >> 8;
    int q0 = (logical & 255) * 16;
    int t = threadIdx.x;
    int lane = t & 63, w = t >> 6;
    int g = lane >> 4, c = lane & 15;

    const short* qp = qm + (size_t)b * S_ * C_;
    const short* kp = km + (size_t)b * S_ * C_;
    const short* vp = vt + (size_t)b * S_ * C_;   // tiled: [4 mi][128 t][512]

    // Q^T B-fragments (held for whole loop): lane reads q row (q0+c)
    bf16x8 bqf[2];
    bqf[0] = *(const bf16x8*)(qp + (q0 + c) * C_ + 8 * g);
    bqf[1] = *(const bf16x8*)(qp + (q0 + c) * C_ + 32 + 8 * g);

    floatx4 oacc[4];
#pragma unroll
    for (int n = 0; n < 4; ++n) oacc[n] = (floatx4){0.f, 0.f, 0.f, 0.f};
    float m = -__builtin_inff(), lsum = 0.f;

    const int addr0 = ((2 * (g & 1)) * 16 + c) * 4;  // bpermute src lane*4
    const int addr1 = addr0 + 64;
    const bool kbhi = (g >> 1) != 0;

    const int kv_beg = w * (S_ / 4), kv_end_ = kv_beg + S_ / 4;
    for (int kv0 = kv_beg; kv0 < kv_end_; kv0 += 32) {
        // ---- S^T tile = K @ Q^T  (swapped so stats are per-lane) ----
        floatx4 st0 = {0.f, 0.f, 0.f, 0.f}, st1 = {0.f, 0.f, 0.f, 0.f};
#pragma unroll
        for (int kk = 0; kk < 2; ++kk) {
            bf16x8 ak0 = *(const bf16x8*)(kp + (kv0 + c) * C_ + 32 * kk + 8 * g);
            bf16x8 ak1 = *(const bf16x8*)(kp + (kv0 + 16 + c) * C_ + 32 * kk + 8 * g);
            st0 = __builtin_amdgcn_mfma_f32_16x16x32_bf16(ak0, bqf[kk], st0, 0, 0, 0);
            st1 = __builtin_amdgcn_mfma_f32_16x16x32_bf16(ak1, bqf[kk], st1, 0, 0, 0);
        }

        // ---- online softmax (q = q0 + c per lane; scores pre-scaled to log2 domain) ----
        float mt = st0[0];
        mt = fmaxf(mt, st0[1]); mt = fmaxf(mt, st0[2]); mt = fmaxf(mt, st0[3]);
        mt = fmaxf(mt, st1[0]); mt = fmaxf(mt, st1[1]);
        mt = fmaxf(mt, st1[2]); mt = fmaxf(mt, st1[3]);
        mt = fmaxf(mt, __shfl_xor(mt, 16));
        mt = fmaxf(mt, __shfl_xor(mt, 32));
        float mnew  = fmaxf(m, mt);
        float alpha = __builtin_amdgcn_exp2f(m - mnew);
        float p0[4], p1[4], psum = 0.f;
#pragma unroll
        for (int r = 0; r < 4; ++r) {
            p0[r] = __builtin_amdgcn_exp2f(st0[r] - mnew);
            p1[r] = __builtin_amdgcn_exp2f(st1[r] - mnew);
            psum += p0[r] + p1[r];
        }
        lsum = lsum * alpha + psum;
        m = mnew;
#pragma unroll
        for (int n = 0; n < 4; ++n) oacc[n] *= alpha;

        // ---- redistribute P^T into PV B-fragment via bpermute ----
        unsigned pk00 = cvt_pk_bf16(p0[0], p0[1]);
        unsigned pk01 = cvt_pk_bf16(p0[2], p0[3]);
        unsigned pk10 = cvt_pk_bf16(p1[0], p1[1]);
        unsigned pk11 = cvt_pk_bf16(p1[2], p1[3]);
        int w0a = __builtin_amdgcn_ds_bpermute(addr0, (int)pk00);
        int w0b = __builtin_amdgcn_ds_bpermute(addr0, (int)pk10);
        int w1a = __builtin_amdgcn_ds_bpermute(addr0, (int)pk01);
        int w1b = __builtin_amdgcn_ds_bpermute(addr0, (int)pk11);
        int w2a = __builtin_amdgcn_ds_bpermute(addr1, (int)pk00);
        int w2b = __builtin_amdgcn_ds_bpermute(addr1, (int)pk10);
        int w3a = __builtin_amdgcn_ds_bpermute(addr1, (int)pk01);
        int w3b = __builtin_amdgcn_ds_bpermute(addr1, (int)pk11);
        intx4 bpw;
        bpw[0] = kbhi ? w0b : w0a;
        bpw[1] = kbhi ? w1b : w1a;
        bpw[2] = kbhi ? w2b : w2a;
        bpw[3] = kbhi ? w3b : w3a;
        bf16x8 bp = __builtin_bit_cast(bf16x8, bpw);

        // ---- O^T += V^T @ P^T (V tiled: contiguous 1KB per (mi, kv-tile)) ----
#pragma unroll
        for (int mi = 0; mi < 4; ++mi) {
            bf16x8 av = *(const bf16x8*)(vp + ((size_t)mi * 128 + (kv0 >> 5)) * 512 + c * 32 + 8 * g);
            oacc[mi] = __builtin_amdgcn_mfma_f32_16x16x32_bf16(av, bp, oacc[mi], 0, 0, 0);
        }
    }

    // ---- per-wave finalize: reduce l across lane groups, publish partials ----
    lsum += __shfl_xor(lsum, 16);
    lsum += __shfl_xor(lsum, 32);
    if (lane < 16) {
        ml[w][0][lane] = m;
        ml[w][1][lane] = lsum;
    }
#pragma unroll
    for (int mi = 0; mi < 4; ++mi)
#pragma unroll
        for (int r = 0; r < 4; ++r)
            part[w][c][16 * mi + 4 * g + r] = oacc[mi][r];
    __syncthreads();

    // ---- cross-wave LSE combine -> bf16 o tile in obuf ----
#pragma unroll
    for (int i = 0; i < 4; ++i) {
        int idx = t + 256 * i;
        int q = idx >> 6, ch = idx & 63;
        float m0 = ml[0][0][q], m1 = ml[1][0][q], m2 = ml[2][0][q], m3 = ml[3][0][q];
        float M = fmaxf(fmaxf(m0, m1), fmaxf(m2, m3));
        float s0 = __builtin_amdgcn_exp2f(m0 - M);
        float s1 = __builtin_amdgcn_exp2f(m1 - M);
        float s2 = __builtin_amdgcn_exp2f(m2 - M);
        float s3 = __builtin_amdgcn_exp2f(m3 - M);
        float L = ml[0][1][q] * s0 + ml[1][1][q] * s1 + ml[2][1][q] * s2 + ml[3][1][q] * s3;
        float v = part[0][q][ch] * s0 + part[1][q][ch] * s1 +
                  part[2][q][ch] * s2 + part[3][q][ch] * s3;
        float o = v / L;
        int off = q * 128 + ch * 2;
        off ^= (q & 7) << 4;
        *(short*)(obuf + off) = f2bf(o);
    }
    __syncthreads();

    // ---- epilogue: out = o @ Wo^T + bo + x ; wave w takes output cols 16w..16w+15 ----
    bf16x8 ao[2];
    {
        int off0 = c * 128 + (8 * g) * 2;        off0 ^= (c & 7) << 4;
        int off1 = c * 128 + (32 + 8 * g) * 2;   off1 ^= (c & 7) << 4;
        ao[0] = *(const bf16x8*)(obuf + off0);
        ao[1] = *(const bf16x8*)(obuf + off1);
    }
    floatx4 a = {0.f, 0.f, 0.f, 0.f};
#pragma unroll
    for (int kk = 0; kk < 2; ++kk) {
        bf16x8 bw = ld_w_frag(Wo, w, kk, g, c);
        a = __builtin_amdgcn_mfma_f32_16x16x32_bf16(ao[kk], bw, a, 0, 0, 0);
    }
    float bov = bo[16 * w + c];
#pragma unroll
    for (int r = 0; r < 4; ++r) {
        int srow = q0 + 4 * g + r;
        size_t idx = ((size_t)b * S_ + srow) * C_ + 16 * w + c;
        out[idx] = x[idx] + bov + a[r];
    }
}

extern "C" void kernel_launch(void* const* d_in, const int* in_sizes, int n_in,
                              void* d_out, int out_size, void* d_ws, size_t ws_size,
                              hipStream_t stream) {
    const float* x  = (const float*)d_in[0];
    // d_in[1] = temb (unused by reference)
    const float* Wq = (const float*)d_in[2];
    const float* bq = (const float*)d_in[3];
    const float* Wk = (const float*)d_in[4];
    const float* bk = (const float*)d_in[5];
    const float* Wv = (const float*)d_in[6];
    const float* bv = (const float*)d_in[7];
    const float* Wo = (const float*)d_in[8];
    const float* bo = (const float*)d_in[9];
    float* out = (float*)d_out;

    char* ws = (char*)d_ws;
    float* partial = (float*)ws;                    // 512 floats
    float* stats   = (float*)(ws + 2048);           // 16 floats
    short* q  = (short*)(ws + 4096);                // [B][S][C] bf16
    short* k  = q + (size_t)B_ * S_ * C_;           // [B][S][C] bf16
    short* vt = k + (size_t)B_ * S_ * C_;           // [B][4][128][512] bf16 tiled V^T

    stats1_kernel<<<256, 256, 0, stream>>>(x, partial);
    stats2_kernel<<<1, 512, 0, stream>>>(partial, stats);
    proj_kernel<<<B_ * (S_ / 64), 256, 0, stream>>>(x, Wq, bq, Wk, bk, Wv, bv, stats, q, k, vt);
    flash_kernel<<<B_ * (S_ / 16), 256, 0, stream>>>(q, k, vt, Wo, bo, x, out);
}

// Round 6
// 108.996 us; speedup vs baseline: 2.4046x; 1.8783x over previous
//
#include <hip/hip_runtime.h>
#include <hip/hip_bf16.h>
#include <math.h>

#define B_ 8
#define S_ 4096
#define C_ 64
#define EPSV 1e-5f

using floatx4 = __attribute__((ext_vector_type(4))) float;
using bf16x8  = __attribute__((ext_vector_type(8))) short;
using intx4   = __attribute__((ext_vector_type(4))) int;

typedef __attribute__((address_space(3))) unsigned int       as3_u32;
typedef __attribute__((address_space(1))) const unsigned int as1_u32;

__device__ __forceinline__ short f2bf(float f) {
    unsigned u = __builtin_bit_cast(unsigned, f);
    u = u + 0x7fffu + ((u >> 16) & 1u);   // RNE
    return (short)(u >> 16);
}

__device__ __forceinline__ unsigned cvt_pk_bf16(float lo, float hi) {
    unsigned r;
    asm volatile("v_cvt_pk_bf16_f32 %0, %1, %2" : "=v"(r) : "v"(lo), "v"(hi));
    return r;
}

// B-fragment from a row-major fp32 64x64 weight matrix.
__device__ __forceinline__ bf16x8 ld_w_frag(const float* __restrict__ W, int n, int kk, int g, int c) {
    const float* p = W + (16 * n + c) * C_ + 32 * kk + 8 * g;
    bf16x8 r;
#pragma unroll
    for (int j = 0; j < 8; ++j) r[j] = f2bf(p[j]);
    return r;
}

// ---------------- kernel 1a: per-chunk partial sums ----------------
__global__ __launch_bounds__(256) void stats1_kernel(const float* __restrict__ x,
                                                     float* __restrict__ partial) {
    int b = blockIdx.x >> 5, chunk = blockIdx.x & 31;
    const float4* xb = (const float4*)x + (size_t)b * 65536 + chunk * 2048;
    float s = 0.f, ss = 0.f;
#pragma unroll
    for (int i = 0; i < 8; ++i) {
        float4 v = xb[threadIdx.x + i * 256];
        s  += v.x + v.y + v.z + v.w;
        ss += v.x * v.x + v.y * v.y + v.z * v.z + v.w * v.w;
    }
    for (int off = 32; off > 0; off >>= 1) {
        s  += __shfl_down(s, off);
        ss += __shfl_down(ss, off);
    }
    __shared__ float sm[4], ssm[4];
    int wid = threadIdx.x >> 6, lane = threadIdx.x & 63;
    if (lane == 0) { sm[wid] = s; ssm[wid] = ss; }
    __syncthreads();
    if (threadIdx.x == 0) {
        partial[blockIdx.x * 2]     = sm[0] + sm[1] + sm[2] + sm[3];
        partial[blockIdx.x * 2 + 1] = ssm[0] + ssm[1] + ssm[2] + ssm[3];
    }
}

// ---------------- kernel 1b: finalize mean / rsqrt(var) ----------------
__global__ __launch_bounds__(512) void stats2_kernel(const float* __restrict__ partial,
                                                     float* __restrict__ stats) {
    int w = threadIdx.x >> 6, lane = threadIdx.x & 63;  // wave w = batch w
    float s = 0.f, ss = 0.f;
    if (lane < 32) {
        s  = partial[(w * 32 + lane) * 2];
        ss = partial[(w * 32 + lane) * 2 + 1];
    }
    for (int off = 16; off > 0; off >>= 1) {
        s  += __shfl_down(s, off);
        ss += __shfl_down(ss, off);
    }
    if (lane == 0) {
        const float invN = 1.0f / (float)(S_ * C_);
        float mu  = s * invN;
        float var = ss * invN - mu * mu;
        stats[w * 2]     = mu;
        stats[w * 2 + 1] = rsqrtf(var + EPSV);
    }
}

// ---------------- kernel 2: normalize + Q/K/V^T projections ----------------
// K and V^T are written as per-64-kv TILE IMAGES (8192 B each), XOR-swizzled
// exactly as the flash kernel's LDS wants them, so flash can DMA them linearly
// with global_load_lds and do conflict-free swizzled ds_reads (both-sides rule).
//   K tile:  [64 kv-rows][64 ch] bf16, byte = (r*128 + ch*2) ^ ((r&7)<<4)
//   V tile:  [64 ch-rows][64 kv] bf16, byte = (ch*128 + u*2) ^ ((ch&7)<<4)
__global__ __launch_bounds__(256) void proj_kernel(
    const float* __restrict__ x,
    const float* __restrict__ Wq, const float* __restrict__ bq,
    const float* __restrict__ Wk, const float* __restrict__ bk,
    const float* __restrict__ Wv, const float* __restrict__ bv,
    const float* __restrict__ stats,
    short* __restrict__ qo, char* __restrict__ kws, char* __restrict__ vws) {
    __shared__ char hbuf[64 * 128];  // [64 rows][64 bf16], XOR-swizzled

    int b  = blockIdx.x >> 6;
    int t_ = blockIdx.x & 63;        // 64-row tile index within batch
    int s0 = t_ * 64;
    float mu = stats[b * 2], rs = stats[b * 2 + 1];
    const float* xt = x + ((size_t)b * S_ + s0) * C_;
    int t = threadIdx.x;

#pragma unroll
    for (int i = 0; i < 4; ++i) {
        int fi  = t + 256 * i;       // float4 index within 64x64 tile
        int row = fi >> 4;
        int c4  = fi & 15;
        float4 v = *(const float4*)(xt + row * C_ + c4 * 4);
        unsigned lo = (unsigned)(unsigned short)f2bf((v.x - mu) * rs) |
                      ((unsigned)(unsigned short)f2bf((v.y - mu) * rs) << 16);
        unsigned hi = (unsigned)(unsigned short)f2bf((v.z - mu) * rs) |
                      ((unsigned)(unsigned short)f2bf((v.w - mu) * rs) << 16);
        int off = row * 128 + c4 * 8;
        off ^= (row & 7) << 4;
        *(uint2*)(hbuf + off) = make_uint2(lo, hi);
    }
    __syncthreads();

    int lane = t & 63, w = t >> 6;
    int g = lane >> 4, c = lane & 15;

    auto ld_h = [&](int row, int kcol) -> bf16x8 {
        int off = row * 128 + kcol * 2;
        off ^= (row & 7) << 4;
        return *(const bf16x8*)(hbuf + off);
    };

    size_t tilebase = ((size_t)b * 64 + t_) * 8192;

    // ---- Q and K: D = h @ W^T.  A = h rows 16w..16w+15 ----
    bf16x8 ha[2];
    ha[0] = ld_h(16 * w + c, 8 * g);
    ha[1] = ld_h(16 * w + c, 32 + 8 * g);

    const float QSC = 0.125f * 1.44269504088896340736f;  // C^-0.5 * log2(e)

#pragma unroll
    for (int n = 0; n < 4; ++n) {
        floatx4 aq = {0.f, 0.f, 0.f, 0.f}, ak = {0.f, 0.f, 0.f, 0.f};
#pragma unroll
        for (int kk = 0; kk < 2; ++kk) {
            bf16x8 wq = ld_w_frag(Wq, n, kk, g, c);
            bf16x8 wk = ld_w_frag(Wk, n, kk, g, c);
            aq = __builtin_amdgcn_mfma_f32_16x16x32_bf16(ha[kk], wq, aq, 0, 0, 0);
            ak = __builtin_amdgcn_mfma_f32_16x16x32_bf16(ha[kk], wk, ak, 0, 0, 0);
        }
        float bqv = bq[16 * n + c], bkv = bk[16 * n + c];
#pragma unroll
        for (int r = 0; r < 4; ++r) {
            int rr = 16 * w + 4 * g + r;          // kv row within tile
            qo[((size_t)b * S_ + s0 + rr) * C_ + 16 * n + c] = f2bf((aq[r] + bqv) * QSC);
            int koff = (rr * 128 + (16 * n + c) * 2) ^ ((rr & 7) << 4);
            *(short*)(kws + tilebase + koff) = f2bf(ak[r] + bkv);
        }
    }

    // ---- V^T = Wv @ h^T (direct transposed, swizzled tile image) ----
    bf16x8 wv[2];
    wv[0] = ld_w_frag(Wv, w, 0, g, c);
    wv[1] = ld_w_frag(Wv, w, 1, g, c);
    float bvr[4];
#pragma unroll
    for (int r = 0; r < 4; ++r) bvr[r] = bv[16 * w + 4 * g + r];

#pragma unroll
    for (int n = 0; n < 4; ++n) {
        floatx4 av = {0.f, 0.f, 0.f, 0.f};
#pragma unroll
        for (int kk = 0; kk < 2; ++kk) {
            bf16x8 hb = ld_h(16 * n + c, 32 * kk + 8 * g);
            av = __builtin_amdgcn_mfma_f32_16x16x32_bf16(wv[kk], hb, av, 0, 0, 0);
        }
#pragma unroll
        for (int r = 0; r < 4; ++r) {
            int rr = 16 * w + 4 * g + r;          // channel row
            int u  = 16 * n + c;                  // kv col within tile
            int voff = (rr * 128 + u * 2) ^ ((rr & 7) << 4);
            *(short*)(vws + tilebase + voff) = f2bf(av[r] + bvr[r]);
        }
    }
}

// ---------------- kernel 3: shared-KV flash attention + Wo + residual ----------------
// Block = 64 q rows (wave w owns rows q0+16w..+15), full KV sweep with K/V
// tiles (64 kv) DMA-staged into LDS once per block, double-buffered.
__global__ __launch_bounds__(256) void flash_kernel(
    const short* __restrict__ qm, const char* __restrict__ kws, const char* __restrict__ vws,
    const float* __restrict__ Wo, const float* __restrict__ bo,
    const float* __restrict__ x, float* __restrict__ out) {
    __shared__ char kb[2][8192];
    __shared__ char vb[2][8192];
    __shared__ char obuf[4][2048];

    int bid = blockIdx.x;
    int logical = (bid & 7) * 64 + (bid >> 3);  // XCD swizzle: batch b -> XCD b
    int b = logical >> 6;
    int q0 = (logical & 63) * 64;
    int t = threadIdx.x;
    int lane = t & 63, w = t >> 6;
    int g = lane >> 4, c = lane & 15;
    int qw = q0 + 16 * w;

    const char* kbase = kws + (size_t)b * 64 * 8192;
    const char* vbase = vws + (size_t)b * 64 * 8192;
    const short* qp = qm + (size_t)b * S_ * C_;

    // Q^T B-fragments (held for whole loop): lane reads q row (qw+c)
    bf16x8 bqf[2];
    bqf[0] = *(const bf16x8*)(qp + (qw + c) * C_ + 8 * g);
    bqf[1] = *(const bf16x8*)(qp + (qw + c) * C_ + 32 + 8 * g);

    floatx4 oacc[4];
#pragma unroll
    for (int n = 0; n < 4; ++n) oacc[n] = (floatx4){0.f, 0.f, 0.f, 0.f};
    float m = -__builtin_inff(), lsum = 0.f;

    const int addr0 = ((2 * (g & 1)) * 16 + c) * 4;  // bpermute src lane*4
    const int addr1 = addr0 + 64;
    const bool kbhi = (g >> 1) != 0;
    const int xmask = (c & 7) << 4;   // per-lane row-swizzle mask (bits 4-6)

    auto STAGE = [&](int bi, int tt) {
        const char* gk = kbase + (size_t)tt * 8192 + w * 2048 + lane * 16;
        const char* gv = vbase + (size_t)tt * 8192 + w * 2048 + lane * 16;
        char* lk = &kb[bi][w * 2048];
        char* lv = &vb[bi][w * 2048];
        __builtin_amdgcn_global_load_lds((as1_u32*)gk,          (as3_u32*)lk,          16, 0, 0);
        __builtin_amdgcn_global_load_lds((as1_u32*)(gk + 1024), (as3_u32*)(lk + 1024), 16, 0, 0);
        __builtin_amdgcn_global_load_lds((as1_u32*)gv,          (as3_u32*)lv,          16, 0, 0);
        __builtin_amdgcn_global_load_lds((as1_u32*)(gv + 1024), (as3_u32*)(lv + 1024), 16, 0, 0);
    };

    // swizzled tile read: row = 16*subtile + c, column bytes colb (multiple of 16)
    auto ld_tile = [&](const char* buf, int subtile, int colb) -> bf16x8 {
        return *(const bf16x8*)(buf + subtile * 2048 + c * 128 + (colb ^ xmask));
    };

    auto COMPUTE = [&](const char* kbuf, const char* vbuf) {
        // ---- S^T (64 kv x 16 q) = K @ Q^T ----
        floatx4 st[4];
#pragma unroll
        for (int s = 0; s < 4; ++s) {
            st[s] = (floatx4){0.f, 0.f, 0.f, 0.f};
#pragma unroll
            for (int kk = 0; kk < 2; ++kk) {
                bf16x8 ak = ld_tile(kbuf, s, 64 * kk + 16 * g);
                st[s] = __builtin_amdgcn_mfma_f32_16x16x32_bf16(ak, bqf[kk], st[s], 0, 0, 0);
            }
        }
        // ---- online softmax (q = qw + c per lane; log2-domain scores) ----
        float mt = st[0][0];
#pragma unroll
        for (int s = 0; s < 4; ++s)
#pragma unroll
            for (int r = 0; r < 4; ++r) mt = fmaxf(mt, st[s][r]);
        mt = fmaxf(mt, __shfl_xor(mt, 16));
        mt = fmaxf(mt, __shfl_xor(mt, 32));
        // defer-max (T13): skip rescale unless max grew by > 8 (p bounded by 2^8)
        if (!__all(mt - m <= 8.0f)) {
            float mnew  = fmaxf(m, mt);
            float alpha = __builtin_amdgcn_exp2f(m - mnew);
            lsum *= alpha;
            m = mnew;
#pragma unroll
            for (int n = 0; n < 4; ++n) oacc[n] *= alpha;
        }
        float p[16], psum = 0.f;
#pragma unroll
        for (int s = 0; s < 4; ++s)
#pragma unroll
            for (int r = 0; r < 4; ++r) {
                p[s * 4 + r] = __builtin_amdgcn_exp2f(st[s][r] - m);
                psum += p[s * 4 + r];
            }
        lsum += psum;

        // ---- redistribute P^T into PV B-fragments + O^T += V^T @ P^T ----
#pragma unroll
        for (int j = 0; j < 2; ++j) {
            unsigned pk00 = cvt_pk_bf16(p[8 * j + 0], p[8 * j + 1]);
            unsigned pk01 = cvt_pk_bf16(p[8 * j + 2], p[8 * j + 3]);
            unsigned pk10 = cvt_pk_bf16(p[8 * j + 4], p[8 * j + 5]);
            unsigned pk11 = cvt_pk_bf16(p[8 * j + 6], p[8 * j + 7]);
            int w0a = __builtin_amdgcn_ds_bpermute(addr0, (int)pk00);
            int w0b = __builtin_amdgcn_ds_bpermute(addr0, (int)pk10);
            int w1a = __builtin_amdgcn_ds_bpermute(addr0, (int)pk01);
            int w1b = __builtin_amdgcn_ds_bpermute(addr0, (int)pk11);
            int w2a = __builtin_amdgcn_ds_bpermute(addr1, (int)pk00);
            int w2b = __builtin_amdgcn_ds_bpermute(addr1, (int)pk10);
            int w3a = __builtin_amdgcn_ds_bpermute(addr1, (int)pk01);
            int w3b = __builtin_amdgcn_ds_bpermute(addr1, (int)pk11);
            intx4 bpw;
            bpw[0] = kbhi ? w0b : w0a;
            bpw[1] = kbhi ? w1b : w1a;
            bpw[2] = kbhi ? w2b : w2a;
            bpw[3] = kbhi ? w3b : w3a;
            bf16x8 bp = __builtin_bit_cast(bf16x8, bpw);
#pragma unroll
            for (int mi = 0; mi < 4; ++mi) {
                bf16x8 av = ld_tile(vbuf, mi, 64 * j + 16 * g);
                oacc[mi] = __builtin_amdgcn_mfma_f32_16x16x32_bf16(av, bp, oacc[mi], 0, 0, 0);
            }
        }
    };

    STAGE(0, 0);
    __syncthreads();
    for (int tt = 0; tt < 64; tt += 2) {
        STAGE(1, tt + 1);
        COMPUTE(kb[0], vb[0]);
        __syncthreads();
        if (tt + 2 < 64) STAGE(0, tt + 2);
        COMPUTE(kb[1], vb[1]);
        __syncthreads();
    }

    // ---- finalize: l reduce, normalize, per-wave transpose O via LDS ----
    lsum += __shfl_xor(lsum, 16);
    lsum += __shfl_xor(lsum, 32);
    float inv = 1.0f / lsum;

    char* ob = obuf[w];
#pragma unroll
    for (int mi = 0; mi < 4; ++mi) {
#pragma unroll
        for (int h = 0; h < 2; ++h) {
            unsigned pkv = cvt_pk_bf16(oacc[mi][2 * h] * inv, oacc[mi][2 * h + 1] * inv);
            int off = (c * 128 + (16 * mi + 4 * g + 2 * h) * 2) ^ ((c & 7) << 4);
            *(unsigned*)(ob + off) = pkv;
        }
    }
    __syncthreads();

    bf16x8 ao[2];
    {
        int off0 = (c * 128 + (8 * g) * 2)      ^ ((c & 7) << 4);
        int off1 = (c * 128 + (32 + 8 * g) * 2) ^ ((c & 7) << 4);
        ao[0] = *(const bf16x8*)(ob + off0);
        ao[1] = *(const bf16x8*)(ob + off1);
    }

    // out = o @ Wo^T + bo + x
#pragma unroll
    for (int n = 0; n < 4; ++n) {
        floatx4 a = {0.f, 0.f, 0.f, 0.f};
#pragma unroll
        for (int kk = 0; kk < 2; ++kk) {
            bf16x8 bw = ld_w_frag(Wo, n, kk, g, c);
            a = __builtin_amdgcn_mfma_f32_16x16x32_bf16(ao[kk], bw, a, 0, 0, 0);
        }
        float bov = bo[16 * n + c];
#pragma unroll
        for (int r = 0; r < 4; ++r) {
            int srow = qw + 4 * g + r;
            size_t idx = ((size_t)b * S_ + srow) * C_ + 16 * n + c;
            out[idx] = x[idx] + bov + a[r];
        }
    }
}

extern "C" void kernel_launch(void* const* d_in, const int* in_sizes, int n_in,
                              void* d_out, int out_size, void* d_ws, size_t ws_size,
                              hipStream_t stream) {
    const float* x  = (const float*)d_in[0];
    // d_in[1] = temb (unused by reference)
    const float* Wq = (const float*)d_in[2];
    const float* bq = (const float*)d_in[3];
    const float* Wk = (const float*)d_in[4];
    const float* bk = (const float*)d_in[5];
    const float* Wv = (const float*)d_in[6];
    const float* bv = (const float*)d_in[7];
    const float* Wo = (const float*)d_in[8];
    const float* bo = (const float*)d_in[9];
    float* out = (float*)d_out;

    char* ws = (char*)d_ws;
    float* partial = (float*)ws;                    // 512 floats
    float* stats   = (float*)(ws + 2048);           // 16 floats
    short* q  = (short*)(ws + 4096);                // [B][S][C] bf16 (4 MB)
    char*  kt = (char*)(q + (size_t)B_ * S_ * C_);  // [B][64 tiles][8192 B] swizzled K
    char*  vt = kt + (size_t)B_ * 64 * 8192;        // [B][64 tiles][8192 B] swizzled V^T

    stats1_kernel<<<256, 256, 0, stream>>>(x, partial);
    stats2_kernel<<<1, 512, 0, stream>>>(partial, stats);
    proj_kernel<<<B_ * (S_ / 64), 256, 0, stream>>>(x, Wq, bq, Wk, bk, Wv, bv, stats, q, kt, vt);
    flash_kernel<<<B_ * (S_ / 64), 256, 0, stream>>>(q, kt, vt, Wo, bo, x, out);
}

// Round 7
// 101.289 us; speedup vs baseline: 2.5876x; 1.0761x over previous
//
#include <hip/hip_runtime.h>
#include <hip/hip_bf16.h>
#include <math.h>

#define B_ 8
#define S_ 4096
#define C_ 64
#define EPSV 1e-5f

using floatx4 = __attribute__((ext_vector_type(4))) float;
using bf16x8  = __attribute__((ext_vector_type(8))) short;
using bf16x4  = __attribute__((ext_vector_type(4))) short;

typedef __attribute__((address_space(3))) unsigned int       as3_u32;
typedef __attribute__((address_space(1))) const unsigned int as1_u32;

__device__ __forceinline__ short f2bf(float f) {
    unsigned u = __builtin_bit_cast(unsigned, f);
    u = u + 0x7fffu + ((u >> 16) & 1u);   // RNE
    return (short)(u >> 16);
}

__device__ __forceinline__ unsigned cvt_pk_bf16(float lo, float hi) {
    unsigned r;
    asm volatile("v_cvt_pk_bf16_f32 %0, %1, %2" : "=v"(r) : "v"(lo), "v"(hi));
    return r;
}

// PV MFMA: 16x16x16 bf16 (K=16) — B-fragment layout (col=c, k=4g+j) matches
// the swapped-QK^T accumulator layout directly -> no cross-lane redistribution.
__device__ __forceinline__ floatx4 mfma_16x16x16_bf16(bf16x4 a, bf16x4 b, floatx4 c) {
#if __has_builtin(__builtin_amdgcn_mfma_f32_16x16x16bf16_1k)
    return __builtin_amdgcn_mfma_f32_16x16x16bf16_1k(a, b, c, 0, 0, 0);
#else
    asm("v_mfma_f32_16x16x16_bf16 %0, %1, %2, %0" : "+v"(c) : "v"(a), "v"(b));
    return c;
#endif
}

// B-fragment from a row-major fp32 64x64 weight matrix.
__device__ __forceinline__ bf16x8 ld_w_frag(const float* __restrict__ W, int n, int kk, int g, int c) {
    const float* p = W + (16 * n + c) * C_ + 32 * kk + 8 * g;
    bf16x8 r;
#pragma unroll
    for (int j = 0; j < 8; ++j) r[j] = f2bf(p[j]);
    return r;
}

// ---------------- kernel 1a: per-chunk partial sums ----------------
__global__ __launch_bounds__(256) void stats1_kernel(const float* __restrict__ x,
                                                     float* __restrict__ partial) {
    int b = blockIdx.x >> 5, chunk = blockIdx.x & 31;
    const float4* xb = (const float4*)x + (size_t)b * 65536 + chunk * 2048;
    float s = 0.f, ss = 0.f;
#pragma unroll
    for (int i = 0; i < 8; ++i) {
        float4 v = xb[threadIdx.x + i * 256];
        s  += v.x + v.y + v.z + v.w;
        ss += v.x * v.x + v.y * v.y + v.z * v.z + v.w * v.w;
    }
    for (int off = 32; off > 0; off >>= 1) {
        s  += __shfl_down(s, off);
        ss += __shfl_down(ss, off);
    }
    __shared__ float sm[4], ssm[4];
    int wid = threadIdx.x >> 6, lane = threadIdx.x & 63;
    if (lane == 0) { sm[wid] = s; ssm[wid] = ss; }
    __syncthreads();
    if (threadIdx.x == 0) {
        partial[blockIdx.x * 2]     = sm[0] + sm[1] + sm[2] + sm[3];
        partial[blockIdx.x * 2 + 1] = ssm[0] + ssm[1] + ssm[2] + ssm[3];
    }
}

// ---------------- kernel 1b: finalize mean / rsqrt(var) ----------------
__global__ __launch_bounds__(512) void stats2_kernel(const float* __restrict__ partial,
                                                     float* __restrict__ stats) {
    int w = threadIdx.x >> 6, lane = threadIdx.x & 63;  // wave w = batch w
    float s = 0.f, ss = 0.f;
    if (lane < 32) {
        s  = partial[(w * 32 + lane) * 2];
        ss = partial[(w * 32 + lane) * 2 + 1];
    }
    for (int off = 16; off > 0; off >>= 1) {
        s  += __shfl_down(s, off);
        ss += __shfl_down(ss, off);
    }
    if (lane == 0) {
        const float invN = 1.0f / (float)(S_ * C_);
        float mu  = s * invN;
        float var = ss * invN - mu * mu;
        stats[w * 2]     = mu;
        stats[w * 2 + 1] = rsqrtf(var + EPSV);
    }
}

// ---------------- kernel 2: normalize + Q/K/V^T projections ----------------
// K and V^T are written as per-64-kv TILE IMAGES (8192 B each), XOR-swizzled
// exactly as the flash kernel's LDS wants them, so flash can DMA them linearly
// with global_load_lds and do conflict-free swizzled ds_reads (both-sides rule).
//   K tile:  [64 kv-rows][64 ch] bf16, byte = (r*128 + ch*2) ^ ((r&7)<<4)
//   V tile:  [64 ch-rows][64 kv] bf16, byte = (ch*128 + u*2) ^ ((ch&7)<<4)
__global__ __launch_bounds__(256) void proj_kernel(
    const float* __restrict__ x,
    const float* __restrict__ Wq, const float* __restrict__ bq,
    const float* __restrict__ Wk, const float* __restrict__ bk,
    const float* __restrict__ Wv, const float* __restrict__ bv,
    const float* __restrict__ stats,
    short* __restrict__ qo, char* __restrict__ kws, char* __restrict__ vws) {
    __shared__ char hbuf[64 * 128];  // [64 rows][64 bf16], XOR-swizzled

    int b  = blockIdx.x >> 6;
    int t_ = blockIdx.x & 63;        // 64-row tile index within batch
    int s0 = t_ * 64;
    float mu = stats[b * 2], rs = stats[b * 2 + 1];
    const float* xt = x + ((size_t)b * S_ + s0) * C_;
    int t = threadIdx.x;

#pragma unroll
    for (int i = 0; i < 4; ++i) {
        int fi  = t + 256 * i;       // float4 index within 64x64 tile
        int row = fi >> 4;
        int c4  = fi & 15;
        float4 v = *(const float4*)(xt + row * C_ + c4 * 4);
        unsigned lo = (unsigned)(unsigned short)f2bf((v.x - mu) * rs) |
                      ((unsigned)(unsigned short)f2bf((v.y - mu) * rs) << 16);
        unsigned hi = (unsigned)(unsigned short)f2bf((v.z - mu) * rs) |
                      ((unsigned)(unsigned short)f2bf((v.w - mu) * rs) << 16);
        int off = row * 128 + c4 * 8;
        off ^= (row & 7) << 4;
        *(uint2*)(hbuf + off) = make_uint2(lo, hi);
    }
    __syncthreads();

    int lane = t & 63, w = t >> 6;
    int g = lane >> 4, c = lane & 15;

    auto ld_h = [&](int row, int kcol) -> bf16x8 {
        int off = row * 128 + kcol * 2;
        off ^= (row & 7) << 4;
        return *(const bf16x8*)(hbuf + off);
    };

    size_t tilebase = ((size_t)b * 64 + t_) * 8192;

    // ---- Q and K: D = h @ W^T.  A = h rows 16w..16w+15 ----
    bf16x8 ha[2];
    ha[0] = ld_h(16 * w + c, 8 * g);
    ha[1] = ld_h(16 * w + c, 32 + 8 * g);

    const float QSC = 0.125f * 1.44269504088896340736f;  // C^-0.5 * log2(e)

#pragma unroll
    for (int n = 0; n < 4; ++n) {
        floatx4 aq = {0.f, 0.f, 0.f, 0.f}, ak = {0.f, 0.f, 0.f, 0.f};
#pragma unroll
        for (int kk = 0; kk < 2; ++kk) {
            bf16x8 wq = ld_w_frag(Wq, n, kk, g, c);
            bf16x8 wk = ld_w_frag(Wk, n, kk, g, c);
            aq = __builtin_amdgcn_mfma_f32_16x16x32_bf16(ha[kk], wq, aq, 0, 0, 0);
            ak = __builtin_amdgcn_mfma_f32_16x16x32_bf16(ha[kk], wk, ak, 0, 0, 0);
        }
        float bqv = bq[16 * n + c], bkv = bk[16 * n + c];
#pragma unroll
        for (int r = 0; r < 4; ++r) {
            int rr = 16 * w + 4 * g + r;          // kv row within tile
            qo[((size_t)b * S_ + s0 + rr) * C_ + 16 * n + c] = f2bf((aq[r] + bqv) * QSC);
            int koff = (rr * 128 + (16 * n + c) * 2) ^ ((rr & 7) << 4);
            *(short*)(kws + tilebase + koff) = f2bf(ak[r] + bkv);
        }
    }

    // ---- V^T = Wv @ h^T (direct transposed, swizzled tile image) ----
    bf16x8 wv[2];
    wv[0] = ld_w_frag(Wv, w, 0, g, c);
    wv[1] = ld_w_frag(Wv, w, 1, g, c);
    float bvr[4];
#pragma unroll
    for (int r = 0; r < 4; ++r) bvr[r] = bv[16 * w + 4 * g + r];

#pragma unroll
    for (int n = 0; n < 4; ++n) {
        floatx4 av = {0.f, 0.f, 0.f, 0.f};
#pragma unroll
        for (int kk = 0; kk < 2; ++kk) {
            bf16x8 hb = ld_h(16 * n + c, 32 * kk + 8 * g);
            av = __builtin_amdgcn_mfma_f32_16x16x32_bf16(wv[kk], hb, av, 0, 0, 0);
        }
#pragma unroll
        for (int r = 0; r < 4; ++r) {
            int rr = 16 * w + 4 * g + r;          // channel row
            int u  = 16 * n + c;                  // kv col within tile
            int voff = (rr * 128 + u * 2) ^ ((rr & 7) << 4);
            *(short*)(vws + tilebase + voff) = f2bf(av[r] + bvr[r]);
        }
    }
}

// ---------------- kernel 3: shared-KV flash attention + Wo + residual ----------------
// Block = 64 q rows (wave w owns rows q0+16w..+15), full KV sweep with K/V
// tiles (64 kv) DMA-staged into LDS once per block, double-buffered.
// PV uses 16x16x16 MFMAs so P^T accumulator registers feed B directly (no bpermute).
__global__ __launch_bounds__(256) void flash_kernel(
    const short* __restrict__ qm, const char* __restrict__ kws, const char* __restrict__ vws,
    const float* __restrict__ Wo, const float* __restrict__ bo,
    const float* __restrict__ x, float* __restrict__ out) {
    __shared__ char kb[2][8192];
    __shared__ char vb[2][8192];
    __shared__ char obuf[4][2048];

    int bid = blockIdx.x;
    int logical = (bid & 7) * 64 + (bid >> 3);  // XCD swizzle: batch b -> XCD b
    int b = logical >> 6;
    int q0 = (logical & 63) * 64;
    int t = threadIdx.x;
    int lane = t & 63, w = t >> 6;
    int g = lane >> 4, c = lane & 15;
    int qw = q0 + 16 * w;

    const char* kbase = kws + (size_t)b * 64 * 8192;
    const char* vbase = vws + (size_t)b * 64 * 8192;
    const short* qp = qm + (size_t)b * S_ * C_;

    // Q^T B-fragments (held for whole loop): lane reads q row (qw+c)
    bf16x8 bqf[2];
    bqf[0] = *(const bf16x8*)(qp + (qw + c) * C_ + 8 * g);
    bqf[1] = *(const bf16x8*)(qp + (qw + c) * C_ + 32 + 8 * g);

    floatx4 oacc[4];
#pragma unroll
    for (int n = 0; n < 4; ++n) oacc[n] = (floatx4){0.f, 0.f, 0.f, 0.f};
    float m = -__builtin_inff(), lsum = 0.f;

    const int xmask = (c & 7) << 4;   // per-lane row-swizzle mask (bits 4-6)

    auto STAGE = [&](int bi, int tt) {
        const char* gk = kbase + (size_t)tt * 8192 + w * 2048 + lane * 16;
        const char* gv = vbase + (size_t)tt * 8192 + w * 2048 + lane * 16;
        char* lk = &kb[bi][w * 2048];
        char* lv = &vb[bi][w * 2048];
        __builtin_amdgcn_global_load_lds((as1_u32*)gk,          (as3_u32*)lk,          16, 0, 0);
        __builtin_amdgcn_global_load_lds((as1_u32*)(gk + 1024), (as3_u32*)(lk + 1024), 16, 0, 0);
        __builtin_amdgcn_global_load_lds((as1_u32*)gv,          (as3_u32*)lv,          16, 0, 0);
        __builtin_amdgcn_global_load_lds((as1_u32*)(gv + 1024), (as3_u32*)(lv + 1024), 16, 0, 0);
    };

    // swizzled K read: row = 16*subtile + c, column bytes colb (16B granule)
    auto ld_k = [&](const char* buf, int subtile, int colb) -> bf16x8 {
        return *(const bf16x8*)(buf + subtile * 2048 + c * 128 + (colb ^ xmask));
    };
    // swizzled V read (8B): row = 16*mi + c (channel), kv chunk = 16*s + 4*g
    auto ld_v = [&](const char* buf, int mi, int s) -> bf16x4 {
        return *(const bf16x4*)(buf + mi * 2048 + c * 128 + ((32 * s + 8 * g) ^ xmask));
    };

    auto COMPUTE = [&](const char* kbuf, const char* vbuf) {
        // ---- S^T (64 kv x 16 q) = K @ Q^T ----
        floatx4 st[4];
        __builtin_amdgcn_s_setprio(1);
#pragma unroll
        for (int s = 0; s < 4; ++s) {
            st[s] = (floatx4){0.f, 0.f, 0.f, 0.f};
#pragma unroll
            for (int kk = 0; kk < 2; ++kk) {
                bf16x8 ak = ld_k(kbuf, s, 64 * kk + 16 * g);
                st[s] = __builtin_amdgcn_mfma_f32_16x16x32_bf16(ak, bqf[kk], st[s], 0, 0, 0);
            }
        }
        __builtin_amdgcn_s_setprio(0);
        // ---- online softmax (q = qw + c per lane; log2-domain scores) ----
        float mt = st[0][0];
#pragma unroll
        for (int s = 0; s < 4; ++s)
#pragma unroll
            for (int r = 0; r < 4; ++r) mt = fmaxf(mt, st[s][r]);
        mt = fmaxf(mt, __shfl_xor(mt, 16));
        mt = fmaxf(mt, __shfl_xor(mt, 32));
        // defer-max (T13): skip rescale unless max grew by > 8 (p bounded by 2^8)
        if (!__all(mt - m <= 8.0f)) {
            float mnew  = fmaxf(m, mt);
            float alpha = __builtin_amdgcn_exp2f(m - mnew);
            lsum *= alpha;
            m = mnew;
#pragma unroll
            for (int n = 0; n < 4; ++n) oacc[n] *= alpha;
        }
        // P = exp2(S - m); pack directly into PV B-fragments (k = 4g+j matches!)
        bf16x4 pb[4];
        float psum = 0.f;
#pragma unroll
        for (int s = 0; s < 4; ++s) {
            float e0 = __builtin_amdgcn_exp2f(st[s][0] - m);
            float e1 = __builtin_amdgcn_exp2f(st[s][1] - m);
            float e2 = __builtin_amdgcn_exp2f(st[s][2] - m);
            float e3 = __builtin_amdgcn_exp2f(st[s][3] - m);
            psum += (e0 + e1) + (e2 + e3);
            uint2 u = make_uint2(cvt_pk_bf16(e0, e1), cvt_pk_bf16(e2, e3));
            pb[s] = __builtin_bit_cast(bf16x4, u);
        }
        lsum += psum;

        // ---- O^T += V^T @ P^T  (16 x 16x16x16 MFMA, B = pb[s] direct) ----
        __builtin_amdgcn_s_setprio(1);
#pragma unroll
        for (int s = 0; s < 4; ++s) {
#pragma unroll
            for (int mi = 0; mi < 4; ++mi) {
                bf16x4 av = ld_v(vbuf, mi, s);
                oacc[mi] = mfma_16x16x16_bf16(av, pb[s], oacc[mi]);
            }
        }
        __builtin_amdgcn_s_setprio(0);
    };

    STAGE(0, 0);
    __syncthreads();
    for (int tt = 0; tt < 64; tt += 2) {
        STAGE(1, tt + 1);
        COMPUTE(kb[0], vb[0]);
        __syncthreads();
        if (tt + 2 < 64) STAGE(0, tt + 2);
        COMPUTE(kb[1], vb[1]);
        __syncthreads();
    }

    // ---- finalize: l reduce, normalize, per-wave transpose O via LDS ----
    lsum += __shfl_xor(lsum, 16);
    lsum += __shfl_xor(lsum, 32);
    float inv = 1.0f / lsum;

    char* ob = obuf[w];
#pragma unroll
    for (int mi = 0; mi < 4; ++mi) {
#pragma unroll
        for (int h = 0; h < 2; ++h) {
            unsigned pkv = cvt_pk_bf16(oacc[mi][2 * h] * inv, oacc[mi][2 * h + 1] * inv);
            int off = (c * 128 + (16 * mi + 4 * g + 2 * h) * 2) ^ ((c & 7) << 4);
            *(unsigned*)(ob + off) = pkv;
        }
    }
    __syncthreads();

    bf16x8 ao[2];
    {
        int off0 = (c * 128 + (8 * g) * 2)      ^ ((c & 7) << 4);
        int off1 = (c * 128 + (32 + 8 * g) * 2) ^ ((c & 7) << 4);
        ao[0] = *(const bf16x8*)(ob + off0);
        ao[1] = *(const bf16x8*)(ob + off1);
    }

    // out = o @ Wo^T + bo + x
#pragma unroll
    for (int n = 0; n < 4; ++n) {
        floatx4 a = {0.f, 0.f, 0.f, 0.f};
#pragma unroll
        for (int kk = 0; kk < 2; ++kk) {
            bf16x8 bw = ld_w_frag(Wo, n, kk, g, c);
            a = __builtin_amdgcn_mfma_f32_16x16x32_bf16(ao[kk], bw, a, 0, 0, 0);
        }
        float bov = bo[16 * n + c];
#pragma unroll
        for (int r = 0; r < 4; ++r) {
            int srow = qw + 4 * g + r;
            size_t idx = ((size_t)b * S_ + srow) * C_ + 16 * n + c;
            out[idx] = x[idx] + bov + a[r];
        }
    }
}

extern "C" void kernel_launch(void* const* d_in, const int* in_sizes, int n_in,
                              void* d_out, int out_size, void* d_ws, size_t ws_size,
                              hipStream_t stream) {
    const float* x  = (const float*)d_in[0];
    // d_in[1] = temb (unused by reference)
    const float* Wq = (const float*)d_in[2];
    const float* bq = (const float*)d_in[3];
    const float* Wk = (const float*)d_in[4];
    const float* bk = (const float*)d_in[5];
    const float* Wv = (const float*)d_in[6];
    const float* bv = (const float*)d_in[7];
    const float* Wo = (const float*)d_in[8];
    const float* bo = (const float*)d_in[9];
    float* out = (float*)d_out;

    char* ws = (char*)d_ws;
    float* partial = (float*)ws;                    // 512 floats
    float* stats   = (float*)(ws + 2048);           // 16 floats
    short* q  = (short*)(ws + 4096);                // [B][S][C] bf16 (4 MB)
    char*  kt = (char*)(q + (size_t)B_ * S_ * C_);  // [B][64 tiles][8192 B] swizzled K
    char*  vt = kt + (size_t)B_ * 64 * 8192;        // [B][64 tiles][8192 B] swizzled V^T

    stats1_kernel<<<256, 256, 0, stream>>>(x, partial);
    stats2_kernel<<<1, 512, 0, stream>>>(partial, stats);
    proj_kernel<<<B_ * (S_ / 64), 256, 0, stream>>>(x, Wq, bq, Wk, bk, Wv, bv, stats, q, kt, vt);
    flash_kernel<<<B_ * (S_ / 64), 256, 0, stream>>>(q, kt, vt, Wo, bo, x, out);
}